// Round 1
// baseline (1020.451 us; speedup 1.0000x reference)
//
#include <hip/hip_runtime.h>
#include <hip/hip_bf16.h>

// DeepSeek MoE: router(fp32 vector GEMM) -> top2 -> grouped SwiGLU experts
// (bf16 MFMA, double-buffered LDS weight streaming) -> y_ws + combine.
// B=4 S=2048 H=1024 I=256 E=256 K=2 CAP=256; T=8192 tokens, N=16384 assignments.

#define T_TOK 8192
#define H_DIM 1024
#define I_DIM 256
#define E_NUM 256
#define CAPc  256

typedef short short8 __attribute__((ext_vector_type(8)));   // 8 x bf16 bits
typedef float f32x4  __attribute__((ext_vector_type(4)));

__device__ __forceinline__ short f2b(float f) {             // fp32 -> bf16 (RNE)
    unsigned int u = __float_as_uint(f);
    u += 0x7FFFu + ((u >> 16) & 1u);
    return (short)(u >> 16);
}
__device__ __forceinline__ unsigned int pack2(float a, float b) {
    return (unsigned int)(unsigned short)f2b(a) | ((unsigned int)(unsigned short)f2b(b) << 16);
}

// ---------------- zeroing ----------------
__global__ void zero_cnt_kernel(int4* __restrict__ cnt4) {
    cnt4[threadIdx.x] = make_int4(0, 0, 0, 0);              // 64 threads x int4 = 256 ints
}
__global__ void zero_out_kernel(float4* __restrict__ out4, int n4) {
    int idx = blockIdx.x * blockDim.x + threadIdx.x;
    float4 z = make_float4(0.f, 0.f, 0.f, 0.f);
    int stride = gridDim.x * blockDim.x;
    for (int i = idx; i < n4; i += stride) out4[i] = z;
}

// ---------------- router GEMM: logits[T,E] = x[T,H] @ rw[E,H]^T (fp32) ----------------
__global__ __launch_bounds__(256) void router_gemm(const float* __restrict__ x,
                                                   const float* __restrict__ rw,
                                                   float* __restrict__ logits) {
    __shared__ float xb[64 * 36];
    __shared__ float wb[64 * 36];
    const int tid = threadIdx.x;
    const int m0 = (int)(blockIdx.x >> 2) * 64;
    const int e0 = (int)(blockIdx.x & 3) * 64;
    const int tx = tid & 15, ty = tid >> 4;
    float acc[4][4];
#pragma unroll
    for (int i = 0; i < 4; ++i)
#pragma unroll
        for (int j = 0; j < 4; ++j) acc[i][j] = 0.f;

    const int r0 = tid >> 3, s4 = (tid & 7) * 4;
    for (int k0 = 0; k0 < H_DIM; k0 += 32) {
        __syncthreads();
#pragma unroll
        for (int p = 0; p < 2; ++p) {
            int r = p * 32 + r0;
            *(float4*)&xb[r * 36 + s4] = *(const float4*)&x[(size_t)(m0 + r) * H_DIM + k0 + s4];
            *(float4*)&wb[r * 36 + s4] = *(const float4*)&rw[(size_t)(e0 + r) * H_DIM + k0 + s4];
        }
        __syncthreads();
#pragma unroll 2
        for (int kk = 0; kk < 32; kk += 4) {
            float4 xr[4], wr[4];
#pragma unroll
            for (int i = 0; i < 4; ++i) xr[i] = *(const float4*)&xb[(ty + 16 * i) * 36 + kk];
#pragma unroll
            for (int j = 0; j < 4; ++j) wr[j] = *(const float4*)&wb[(tx + 16 * j) * 36 + kk];
#pragma unroll
            for (int i = 0; i < 4; ++i)
#pragma unroll
                for (int j = 0; j < 4; ++j)
                    acc[i][j] += xr[i].x * wr[j].x + xr[i].y * wr[j].y +
                                 xr[i].z * wr[j].z + xr[i].w * wr[j].w;
        }
    }
#pragma unroll
    for (int i = 0; i < 4; ++i)
#pragma unroll
        for (int j = 0; j < 4; ++j)
            logits[(size_t)(m0 + ty + 16 * i) * E_NUM + (e0 + tx + 16 * j)] = acc[i][j];
}

// ---------------- softmax + top2 + dispatch (one wave per token) ----------------
__global__ __launch_bounds__(256) void topk_kernel(const float* __restrict__ logits,
                                                   int* __restrict__ cnt,
                                                   int* __restrict__ tok_of,
                                                   float* __restrict__ wt_of) {
    const int t = blockIdx.x * 4 + (threadIdx.x >> 6);
    const int l = threadIdx.x & 63;
    float4 lv = *(const float4*)&logits[(size_t)t * E_NUM + l * 4];
    float mx = fmaxf(fmaxf(lv.x, lv.y), fmaxf(lv.z, lv.w));
    for (int o = 32; o; o >>= 1) mx = fmaxf(mx, __shfl_xor(mx, o));
    float se = __expf(lv.x - mx) + __expf(lv.y - mx) + __expf(lv.z - mx) + __expf(lv.w - mx);
    for (int o = 32; o; o >>= 1) se += __shfl_xor(se, o);
    float vals[4] = {lv.x, lv.y, lv.z, lv.w};
    float v1 = -3.4e38f, v2 = -3.4e38f;
    int i1 = 0x7fffffff, i2 = 0x7fffffff;
#pragma unroll
    for (int c = 0; c < 4; ++c) {
        float v = vals[c]; int idx = l * 4 + c;
        if (v > v1 || (v == v1 && idx < i1)) { v2 = v1; i2 = i1; v1 = v; i1 = idx; }
        else if (v > v2 || (v == v2 && idx < i2)) { v2 = v; i2 = idx; }
    }
    for (int o = 1; o < 64; o <<= 1) {
        float ov1 = __shfl_xor(v1, o); int oi1 = __shfl_xor(i1, o);
        float ov2 = __shfl_xor(v2, o); int oi2 = __shfl_xor(i2, o);
        if (ov1 > v1 || (ov1 == v1 && oi1 < i1)) {
            float nv2; int ni2;
            if (v1 > ov2 || (v1 == ov2 && i1 < oi2)) { nv2 = v1; ni2 = i1; }
            else { nv2 = ov2; ni2 = oi2; }
            v1 = ov1; i1 = oi1; v2 = nv2; i2 = ni2;
        } else {
            if (ov1 > v2 || (ov1 == v2 && oi1 < i2)) { v2 = ov1; i2 = oi1; }
        }
    }
    if (l == 0) {
        float p1 = __expf(v1 - mx) / se;
        float p2 = __expf(v2 - mx) / se;
        float ew = __expf(p2 - p1);               // softmax([p1,p2])
        float w1 = 1.f / (1.f + ew);
        float w2 = ew / (1.f + ew);
        int s1 = atomicAdd(&cnt[i1], 1); if (s1 > CAPc - 1) s1 = CAPc - 1;
        tok_of[i1 * CAPc + s1] = 2 * t;     wt_of[i1 * CAPc + s1] = w1;
        int s2 = atomicAdd(&cnt[i2], 1); if (s2 > CAPc - 1) s2 = CAPc - 1;
        tok_of[i2 * CAPc + s2] = 2 * t + 1; wt_of[i2 * CAPc + s2] = w2;
    }
}

// ---------------- per-expert SwiGLU MLP, bf16 MFMA 16x16x32, block = 1 expert ----------------
// 1024 threads = 16 waves (16 waves/CU, 50% occ). M=128.
// Phase1: gate+up fused, K=1024, BK=32, DOUBLE-BUFFERED staging with one barrier per step:
//   issue loads(k+1) -> MFMA on buf[p] -> convert+ds_write buf[p^1] -> barrier.
// Phase2: down, K=256, BK=32, two 512-col halves, same pipeline.
// LDS: dbuf p1 [0,87040) ; acts [0,67584) aliases it ; wds dbuf [67584,134656) ; toks/wts tail.
#define XS_OFF(p)  ((p) * 43520)                 // [128][40] bf16, 10240 B
#define WG_OFF(p)  ((p) * 43520 + 10240)         // [32][260] bf16, 16640 B
#define WU_OFF(p)  ((p) * 43520 + 26880)         // [32][260] bf16, 16640 B
#define ACT_OFF    0                             // [128][264] bf16, 67584 B (aliases phase1)
#define WDS_OFF(p) (67584 + (p) * 33536)         // [32][524] bf16, 33536 B each
#define TOK_OFF    134656
#define WTS_OFF    135168
#define LDS_TOTAL  135680

#define P1_LOAD(ko_) do {                                                           \
    xr_ = xval ? *(const float4*)&x[xb + (ko_) * 32 + xc4]                          \
               : make_float4(0.f, 0.f, 0.f, 0.f);                                   \
    _Pragma("unroll")                                                               \
    for (int s = 0; s < 2; ++s) {                                                   \
        const int f4 = s * 1024 + tid, k = f4 >> 6, c4_ = (f4 & 63) * 4;            \
        const size_t ga = wbase + (size_t)((ko_) * 32 + k) * I_DIM + c4_;           \
        gv[s] = *(const float4*)&wg[ga];                                            \
        uv[s] = *(const float4*)&wu[ga];                                            \
    } } while (0)

#define P1_WRITE(p_) do {                                                           \
    short* xs_ = (short*)(lds + XS_OFF(p_));                                        \
    short* gs_ = (short*)(lds + WG_OFF(p_));                                        \
    short* us_ = (short*)(lds + WU_OFF(p_));                                        \
    *(uint2*)&xs_[xrow * 40 + xc4] =                                                \
        make_uint2(pack2(xr_.x, xr_.y), pack2(xr_.z, xr_.w));                       \
    _Pragma("unroll")                                                               \
    for (int s = 0; s < 2; ++s) {                                                   \
        const int f4 = s * 1024 + tid, k = f4 >> 6, c4_ = (f4 & 63) * 4;            \
        *(uint2*)&gs_[k * 260 + c4_] =                                              \
            make_uint2(pack2(gv[s].x, gv[s].y), pack2(gv[s].z, gv[s].w));           \
        *(uint2*)&us_[k * 260 + c4_] =                                              \
            make_uint2(pack2(uv[s].x, uv[s].y), pack2(uv[s].z, uv[s].w));           \
    } } while (0)

#define P1_COMP(p_) do {                                                            \
    const short* xs_ = (const short*)(lds + XS_OFF(p_));                            \
    const short* gs_ = (const short*)(lds + WG_OFF(p_));                            \
    const short* us_ = (const short*)(lds + WU_OFF(p_));                            \
    const int col_ = w * 16 + l15;                                                  \
    short8 bg, bu;                                                                  \
    _Pragma("unroll")                                                               \
    for (int j = 0; j < 8; ++j) {                                                   \
        bg[j] = gs_[(lq * 8 + j) * 260 + col_];                                     \
        bu[j] = us_[(lq * 8 + j) * 260 + col_];                                     \
    }                                                                               \
    _Pragma("unroll")                                                               \
    for (int mt = 0; mt < 8; ++mt) {                                                \
        short8 a_ = *(const short8*)&xs_[(mt * 16 + l15) * 40 + lq * 8];            \
        accg[mt] = __builtin_amdgcn_mfma_f32_16x16x32_bf16(a_, bg, accg[mt], 0, 0, 0); \
        accu[mt] = __builtin_amdgcn_mfma_f32_16x16x32_bf16(a_, bu, accu[mt], 0, 0, 0); \
    } } while (0)

#define P2_LOAD(half_, ki_) do {                                                    \
    _Pragma("unroll")                                                               \
    for (int s = 0; s < 4; ++s) {                                                   \
        const int f4 = s * 1024 + tid, k = f4 >> 7, c4_ = (f4 & 127) * 4;           \
        dv[s] = *(const float4*)&wd[dbase + (size_t)((ki_) * 32 + k) * H_DIM +      \
                                    (half_) * 512 + c4_];                           \
    } } while (0)

#define P2_WRITE(p_) do {                                                           \
    short* ws_ = (short*)(lds + WDS_OFF(p_));                                       \
    _Pragma("unroll")                                                               \
    for (int s = 0; s < 4; ++s) {                                                   \
        const int f4 = s * 1024 + tid, k = f4 >> 7, c4_ = (f4 & 127) * 4;           \
        *(uint2*)&ws_[k * 524 + c4_] =                                              \
            make_uint2(pack2(dv[s].x, dv[s].y), pack2(dv[s].z, dv[s].w));           \
    } } while (0)

#define P2_COMP(p_, ki_) do {                                                       \
    const short* ws_ = (const short*)(lds + WDS_OFF(p_));                           \
    const short* ac_ = (const short*)(lds + ACT_OFF);                               \
    short8 b0, b1;                                                                  \
    _Pragma("unroll")                                                               \
    for (int j = 0; j < 8; ++j) {                                                   \
        b0[j] = ws_[(lq * 8 + j) * 524 + (w * 32 + l15)];                           \
        b1[j] = ws_[(lq * 8 + j) * 524 + (w * 32 + 16 + l15)];                      \
    }                                                                               \
    _Pragma("unroll")                                                               \
    for (int mt = 0; mt < 8; ++mt) {                                                \
        short8 a_ = *(const short8*)&ac_[(mt * 16 + l15) * 264 + (ki_) * 32 + lq * 8]; \
        acc[mt][0] = __builtin_amdgcn_mfma_f32_16x16x32_bf16(a_, b0, acc[mt][0], 0, 0, 0); \
        acc[mt][1] = __builtin_amdgcn_mfma_f32_16x16x32_bf16(a_, b1, acc[mt][1], 0, 0, 0); \
    } } while (0)

__global__ __launch_bounds__(1024, 4) void expert_kernel(
    const float* __restrict__ x, const float* __restrict__ wg, const float* __restrict__ wu,
    const float* __restrict__ wd, const float* __restrict__ gsc, const float* __restrict__ usc,
    const float* __restrict__ dsc, const int* __restrict__ cnt, const int* __restrict__ tok_of,
    const float* __restrict__ wt_of, float* __restrict__ out, float* __restrict__ y_ws,
    const int use_ws) {
    __shared__ __attribute__((aligned(16))) char lds[LDS_TOTAL];
    int*   toks = (int*)(lds + TOK_OFF);
    float* wts  = (float*)(lds + WTS_OFF);

    const int e = blockIdx.x;
    int c = cnt[e]; if (c > CAPc) c = CAPc;
    if (c == 0) return;
    const float gse = gsc[e], use_ = usc[e], dse = dsc[e];
    const int tid = threadIdx.x;
    const int w = tid >> 6, l = tid & 63, l15 = l & 15, lq = l >> 4;
    const size_t wbase = (size_t)e * (H_DIM * I_DIM);
    const size_t dbase = (size_t)e * (I_DIM * H_DIM);
    const f32x4 z4 = {0.f, 0.f, 0.f, 0.f};

    for (int mc = 0; mc * 128 < c; ++mc) {
        const int rows = min(128, c - mc * 128);
        __syncthreads();                           // LDS reuse across mc iterations
        if (tid < 128) {
            const int idx = mc * 128 + tid;
            toks[tid] = (idx < c) ? tok_of[e * CAPc + idx] : 0;
            wts[tid]  = (idx < c) ? wt_of[e * CAPc + idx] : 0.f;
        }
        __syncthreads();

        // ---- phase 1: gate+up fused over K=1024, BK=32, dbuf pipeline ----
        const int xrow = tid >> 3, xc4 = (tid & 7) * 4;   // 128 rows x 8 threads
        const bool xval = (xrow < rows);
        const size_t xb = xval ? (size_t)(toks[xrow] >> 1) * H_DIM : 0;

        f32x4 accg[8], accu[8];
#pragma unroll
        for (int i = 0; i < 8; ++i) { accg[i] = z4; accu[i] = z4; }
        float4 xr_, gv[2], uv[2];

        P1_LOAD(0);
        P1_WRITE(0);
        __syncthreads();
        for (int ko = 0; ko < 32; ++ko) {
            const int p = ko & 1;
            if (ko < 31) P1_LOAD(ko + 1);          // loads in flight across MFMA
            P1_COMP(p);
            if (ko < 31) P1_WRITE(p ^ 1);          // write other buffer, one barrier
            __syncthreads();
        }

        // ---- phase 1.5: act = silu(g*gs)*(u*us) -> acts (aliases phase-1 buffers) ----
        {
            short* acts = (short*)(lds + ACT_OFF);
            const int colA = w * 16 + l15;
#pragma unroll
            for (int mt = 0; mt < 8; ++mt)
#pragma unroll
                for (int r = 0; r < 4; ++r) {
                    const int row = mt * 16 + lq * 4 + r;
                    float g = accg[mt][r] * gse;
                    float u = accu[mt][r] * use_;
                    acts[row * 264 + colA] = f2b((g / (1.f + __expf(-g))) * u);
                }
        }
        __syncthreads();

        // ---- phase 2: down GEMM, K=256, two 512-col halves, dbuf pipeline ----
        for (int half = 0; half < 2; ++half) {
            f32x4 acc[8][2];
#pragma unroll
            for (int i = 0; i < 8; ++i) { acc[i][0] = z4; acc[i][1] = z4; }
            float4 dv[4];
            P2_LOAD(half, 0);
            P2_WRITE(0);
            __syncthreads();
            for (int ki = 0; ki < 8; ++ki) {
                const int p = ki & 1;
                if (ki < 7) P2_LOAD(half, ki + 1);
                P2_COMP(p, ki);
                if (ki < 7) P2_WRITE(p ^ 1);
                __syncthreads();
            }
#pragma unroll
            for (int mt = 0; mt < 8; ++mt)
#pragma unroll
                for (int r = 0; r < 4; ++r) {
                    const int row = mt * 16 + lq * 4 + r;
                    if (row < rows) {
                        const float wrow = dse * wts[row];
                        const int tk = toks[row];
#pragma unroll
                        for (int nt = 0; nt < 2; ++nt) {
                            const int col = half * 512 + w * 32 + nt * 16 + l15;
                            float v = acc[mt][nt][r] * wrow;
                            if (use_ws) y_ws[(size_t)tk * H_DIM + col] = v;
                            else atomicAdd(&out[(size_t)(tk >> 1) * H_DIM + col], v);
                        }
                    }
                }
        }
    }
}

// ---------------- combine: out[t] = y_ws[2t] + y_ws[2t+1] ----------------
__global__ __launch_bounds__(256) void combine_kernel(const float4* __restrict__ y4,
                                                      float4* __restrict__ out4) {
    const int t = blockIdx.x;
    const int i = threadIdx.x;
    float4 a = y4[(size_t)t * 512 + i];
    float4 b = y4[(size_t)t * 512 + 256 + i];
    out4[(size_t)t * 256 + i] = make_float4(a.x + b.x, a.y + b.y, a.z + b.z, a.w + b.w);
}

extern "C" void kernel_launch(void* const* d_in, const int* in_sizes, int n_in,
                              void* d_out, int out_size, void* d_ws, size_t ws_size,
                              hipStream_t stream) {
    const float* x  = (const float*)d_in[0];
    const float* rw = (const float*)d_in[1];
    const float* wg = (const float*)d_in[2];
    const float* wu = (const float*)d_in[3];
    const float* wd = (const float*)d_in[4];
    const float* gs = (const float*)d_in[5];
    const float* us = (const float*)d_in[6];
    const float* ds = (const float*)d_in[7];
    float* out = (float*)d_out;

    char* ws = (char*)d_ws;
    float* logits = (float*)ws;                        // 8192*256*4 = 8388608 B
    int*   cnt    = (int*)(ws + 8388608);              // 1024 B (pad to 1024)
    int*   tok_of = (int*)(ws + 8389632);              // 262144 B
    float* wt_of  = (float*)(ws + 8651776);            // 262144 B
    float* y_ws   = (float*)(ws + 8913920);            // 16384*1024*4 = 67108864 B
    const size_t need = 8913920ull + 67108864ull;
    const int use_ws = (ws_size >= need) ? 1 : 0;

    zero_cnt_kernel<<<1, 64, 0, stream>>>((int4*)cnt);
    if (!use_ws)
        zero_out_kernel<<<2048, 256, 0, stream>>>((float4*)out, (T_TOK * H_DIM) / 4);
    router_gemm<<<512, 256, 0, stream>>>(x, rw, logits);
    topk_kernel<<<2048, 256, 0, stream>>>(logits, cnt, tok_of, wt_of);
    expert_kernel<<<E_NUM, 1024, 0, stream>>>(x, wg, wu, wd, gs, us, ds, cnt, tok_of, wt_of,
                                              out, y_ws, use_ws);
    if (use_ws)
        combine_kernel<<<T_TOK, 256, 0, stream>>>((const float4*)y_ws, (float4*)out);
}